// Round 16
// baseline (168.635 us; speedup 1.0000x reference)
//
#include <hip/hip_runtime.h>
#include <math.h>

#define D 64
#define NB 256        // blocks per direction for bucket hist/scatter
#define SCAN_NB 256   // blocks per scan pass
#define PS_NB 2048    // pass_src blocks in fused launch

typedef _Float16 hf;
typedef _Float16 hf2 __attribute__((ext_vector_type(2)));

__device__ inline float fdot2f(hf2 a, hf2 b, float c) {
#if __has_builtin(__builtin_amdgcn_fdot2)
    return __builtin_amdgcn_fdot2(a, b, c, false);
#else
    return (float)a[0] * (float)b[0] + (float)a[1] * (float)b[1] + c;
#endif
}

// ---------------- K1: node_pre (4 nodes/thread) FUSED with bucket_hist (LDS union) ----------------
__global__ __launch_bounds__(512) void node_pre_hist_kernel(
    const float* __restrict__ h,
    const float* __restrict__ W_att,
    const float* __restrict__ W_p,
    const float* __restrict__ W_pp,
    const float* __restrict__ phi_w,
    const float* __restrict__ phi_b,
    const float* __restrict__ fdef_w,
    const float* __restrict__ fdef_b,
    const int* __restrict__ tgtI, const int* __restrict__ srcI,
    int* __restrict__ ghist_t, int* __restrict__ ghist_s,
    hf* __restrict__ AW16,
    hf* __restrict__ P16,
    hf* __restrict__ PP16,
    float* __restrict__ enpsi,
    int nNodes, int nbNode, int nBkt, int nEdges)
{
    union SMem {
        struct {
            hf2 sW2[4][32][D];       // 32 KB
            hf  hall[32][D];         // 4 KB
            float sPhib[D];
            float sFdef[D];
        } np;
        int hist[2048];              // 8 KB
    };
    __shared__ SMem sm;

    const int tid = threadIdx.x;

    if (blockIdx.x >= nbNode) {
        // ---------------- bucket_hist branch ----------------
        const int hb = blockIdx.x - nbNode;
        const int dir = hb / NB;
        const int b = hb % NB;
        const int* keys = dir ? srcI : tgtI;
        int* gh = dir ? ghist_s : ghist_t;
        for (int d = tid; d < nBkt; d += 512) sm.hist[d] = 0;
        __syncthreads();
        const int C = (nEdges + NB - 1) / NB;
        const int beg = b * C;
        const int end = min(beg + C, nEdges);
        for (int e = beg + tid; e < end; e += 512)
            atomicAdd(&sm.hist[keys[e] >> 5], 1);
        __syncthreads();
        for (int d = tid; d < nBkt; d += 512)
            gh[(size_t)d * NB + b] = sm.hist[d];
        return;
    }

    // ---------------- node_pre branch ----------------
    const float* Wm[4] = { W_att, W_p, W_pp, phi_w };
    for (int idx = tid; idx < 4 * 32 * D; idx += 512) {
        const int m  = idx >> 11;
        const int k2 = (idx >> 6) & 31;
        const int j  = idx & 63;
        sm.np.sW2[m][k2][j] = hf2{(hf)Wm[m][(2 * k2) * D + j], (hf)Wm[m][(2 * k2 + 1) * D + j]};
    }
    if (tid < D) { sm.np.sPhib[tid] = phi_b[tid]; sm.np.sFdef[tid] = fdef_w[tid]; }
    __syncthreads();
    const float fb = fdef_b[0];

    const int n0 = blockIdx.x * 32;
    {
        const int base = tid * 4;
        const int ln = base >> 6;
        const int col = base & 63;
        const int n = n0 + ln;
        float ps = 0.f;
        if (n < nNodes) {
            const float4 v = *(const float4*)(h + (size_t)n * D + col);
            sm.np.hall[ln][col]     = (hf)v.x;
            sm.np.hall[ln][col + 1] = (hf)v.y;
            sm.np.hall[ln][col + 2] = (hf)v.z;
            sm.np.hall[ln][col + 3] = (hf)v.w;
            ps = v.x * sm.np.sFdef[col] + v.y * sm.np.sFdef[col + 1]
               + v.z * sm.np.sFdef[col + 2] + v.w * sm.np.sFdef[col + 3];
        }
        #pragma unroll
        for (int off = 8; off >= 1; off >>= 1) ps += __shfl_xor(ps, off, 64);
        if ((tid & 15) == 0 && n < nNodes) enpsi[n] = __expf(-(ps + fb));
    }
    __syncthreads();

    const int g = tid >> 6;
    const int j = tid & 63;
    const int ln0 = 4 * g;

    float acc[4][4];
    #pragma unroll
    for (int m = 0; m < 4; ++m) {
        acc[m][0] = 0.f; acc[m][1] = 0.f; acc[m][2] = 0.f; acc[m][3] = sm.np.sPhib[j];
    }
    const hf2* hr0 = (const hf2*)sm.np.hall[ln0 + 0];
    const hf2* hr1 = (const hf2*)sm.np.hall[ln0 + 1];
    const hf2* hr2 = (const hf2*)sm.np.hall[ln0 + 2];
    const hf2* hr3 = (const hf2*)sm.np.hall[ln0 + 3];

    #pragma unroll 8
    for (int k2 = 0; k2 < 32; ++k2) {
        const hf2 w0 = sm.np.sW2[0][k2][j];
        const hf2 w1 = sm.np.sW2[1][k2][j];
        const hf2 w2 = sm.np.sW2[2][k2][j];
        const hf2 w3 = sm.np.sW2[3][k2][j];
        const hf2 h0 = hr0[k2];
        const hf2 h1 = hr1[k2];
        const hf2 h2 = hr2[k2];
        const hf2 h3 = hr3[k2];
        acc[0][0] = fdot2f(w0, h0, acc[0][0]);
        acc[0][1] = fdot2f(w1, h0, acc[0][1]);
        acc[0][2] = fdot2f(w2, h0, acc[0][2]);
        acc[0][3] = fdot2f(w3, h0, acc[0][3]);
        acc[1][0] = fdot2f(w0, h1, acc[1][0]);
        acc[1][1] = fdot2f(w1, h1, acc[1][1]);
        acc[1][2] = fdot2f(w2, h1, acc[1][2]);
        acc[1][3] = fdot2f(w3, h1, acc[1][3]);
        acc[2][0] = fdot2f(w0, h2, acc[2][0]);
        acc[2][1] = fdot2f(w1, h2, acc[2][1]);
        acc[2][2] = fdot2f(w2, h2, acc[2][2]);
        acc[2][3] = fdot2f(w3, h2, acc[2][3]);
        acc[3][0] = fdot2f(w0, h3, acc[3][0]);
        acc[3][1] = fdot2f(w1, h3, acc[3][1]);
        acc[3][2] = fdot2f(w2, h3, acc[3][2]);
        acc[3][3] = fdot2f(w3, h3, acc[3][3]);
    }

    #pragma unroll
    for (int m = 0; m < 4; ++m) {
        const int n = n0 + ln0 + m;
        if (n < nNodes) {
            float a = acc[m][0];
            if (j < 6) a += (float)sm.np.hall[ln0 + m][j];
            const size_t base = (size_t)n * D + j;
            *(hf2*)(AW16 + ((size_t)n << 7) + 2 * j) = hf2{(hf)a, (hf)acc[m][3]};
            P16[base]  = (hf)acc[m][1];
            PP16[base] = (hf)acc[m][2];
        }
    }
}

// ---------------- Scan step 1 ----------------
__global__ __launch_bounds__(256) void scan_partial_kernel(
    const int* __restrict__ in_t, const int* __restrict__ in_s,
    int* __restrict__ bsum, int L)
{
    const int pass = blockIdx.x >> 8;
    const int b = blockIdx.x & (SCAN_NB - 1);
    const int* in = pass ? in_s : in_t;
    const int C = (L + SCAN_NB - 1) / SCAN_NB;
    const int K = (C + 255) / 256;
    const int base = b * C;
    const int lim = min(base + C, L);
    const int tbeg = base + threadIdx.x * K;
    const int tend = min(tbeg + K, lim);
    int tsum = 0;
    for (int i = tbeg; i < tend; ++i) tsum += in[i];
    __shared__ int red[256];
    red[threadIdx.x] = tsum;
    __syncthreads();
    for (int off = 128; off >= 1; off >>= 1) {
        if (threadIdx.x < off) red[threadIdx.x] += red[threadIdx.x + off];
        __syncthreads();
    }
    if (threadIdx.x == 0) bsum[pass * SCAN_NB + b] = red[0];
}

// ---------------- Scan step 2 ----------------
__global__ __launch_bounds__(512) void scan_bsum_kernel(int* __restrict__ bsum)
{
    __shared__ int s[2 * SCAN_NB];
    const int tid = threadIdx.x;
    const int orig = bsum[tid];
    s[tid] = orig;
    __syncthreads();
    const int seg = tid & (SCAN_NB - 1);
    for (int off = 1; off < SCAN_NB; off <<= 1) {
        const int add = (seg >= off) ? s[tid - off] : 0;
        __syncthreads();
        s[tid] += add;
        __syncthreads();
    }
    bsum[tid] = s[tid] - orig;
}

// ---------------- Scan step 3 ----------------
__global__ __launch_bounds__(256) void scan_final_kernel(
    const int* __restrict__ in_t, const int* __restrict__ in_s,
    const int* __restrict__ bsum,
    int* __restrict__ gsc_t, int* __restrict__ gsc_s, int L)
{
    const int pass = blockIdx.x >> 8;
    const int b = blockIdx.x & (SCAN_NB - 1);
    const int* in = pass ? in_s : in_t;
    int* out = pass ? gsc_s : gsc_t;
    const int C = (L + SCAN_NB - 1) / SCAN_NB;
    const int K = (C + 255) / 256;
    const int base = b * C;
    const int lim = min(base + C, L);
    const int tbeg = base + threadIdx.x * K;
    const int tend = min(tbeg + K, lim);
    int tsum = 0;
    for (int i = tbeg; i < tend; ++i) tsum += in[i];
    __shared__ int s[256];
    s[threadIdx.x] = tsum;
    __syncthreads();
    for (int off = 1; off < 256; off <<= 1) {
        const int add = (threadIdx.x >= off) ? s[threadIdx.x - off] : 0;
        __syncthreads();
        s[threadIdx.x] += add;
        __syncthreads();
    }
    int run = s[threadIdx.x] - tsum + bsum[pass * SCAN_NB + b];
    for (int i = tbeg; i < tend; ++i) { out[i] = run; run += in[i]; }
}

// ---------------- Bucket scatter ----------------
__global__ __launch_bounds__(256) void bucket_scatter_kernel(
    const int* __restrict__ tgtI, const int* __restrict__ srcI,
    const int* __restrict__ gsc_t, const int* __restrict__ gsc_s,
    unsigned* __restrict__ ep_t, unsigned* __restrict__ ep_s,
    int nBkt, int nEdges)
{
    __shared__ int cursor[2048];
    const int dir = blockIdx.x / NB;
    const int b = blockIdx.x % NB;
    const int* keys = dir ? srcI : tgtI;
    const int* pays = dir ? tgtI : srcI;
    const int* gsc = dir ? gsc_s : gsc_t;
    unsigned* ep = dir ? ep_s : ep_t;
    const int tid = threadIdx.x;
    for (int d = tid; d < nBkt; d += 256) cursor[d] = gsc[(size_t)d * NB + b];
    __syncthreads();
    const int C = (nEdges + NB - 1) / NB;
    const int beg = b * C;
    const int end = min(beg + C, nEdges);
    for (int e = beg + tid; e < end; e += 256) {
        const unsigned k = (unsigned)keys[e];
        const unsigned p = (unsigned)pays[e];
        const int pos = atomicAdd(&cursor[k >> 5], 1);
        ep[pos] = (k << 16) | p;
    }
}

// ---------------- Per-bucket counting sort body ----------------
__device__ inline void bucket_sort_body(
    const unsigned* __restrict__ ep, const int* __restrict__ gsc,
    int* __restrict__ out, int* __restrict__ rowstart,
    int b, int nBkt, int nNodes, int nEdges,
    int* hist, int* pref, int* cur, int tid)
{
    if (b == 0 && tid == 0) rowstart[nNodes] = nEdges;

    const int s = gsc[(size_t)b * NB];
    const int e = (b + 1 < nBkt) ? gsc[(size_t)(b + 1) * NB] : nEdges;
    const int size = e - s;

    if (tid < 32) hist[tid] = 0;
    __syncthreads();
    for (int i = tid; i < size; i += 256)
        atomicAdd(&hist[(ep[s + i] >> 16) & 31], 1);
    __syncthreads();
    if (tid == 0) {
        int r = 0;
        for (int k = 0; k < 32; ++k) { pref[k] = r; cur[k] = r; r += hist[k]; }
    }
    __syncthreads();
    if (tid < 32) {
        const int key = (b << 5) + tid;
        if (key < nNodes) rowstart[key] = s + pref[tid];
    }
    __syncthreads();
    for (int i = tid; i < size; i += 256) {
        const unsigned v = ep[s + i];
        const int pos = atomicAdd(&cur[(v >> 16) & 31], 1);
        out[s + pos] = (int)(v & 0xFFFFu);
    }
}

// ---------------- Solo s-direction sort ----------------
__global__ __launch_bounds__(256) void bucket_sort_s_kernel(
    const unsigned* __restrict__ ep_s, const int* __restrict__ gsc_s,
    int* __restrict__ tgt_sorted, int* __restrict__ rowstart_s,
    int nBkt, int nNodes, int nEdges)
{
    __shared__ int hist[32], pref[32], cur[32];
    bucket_sort_body(ep_s, gsc_s, tgt_sorted, rowstart_s,
                     blockIdx.x, nBkt, nNodes, nEdges, hist, pref, cur, threadIdx.x);
}

// ---------------- K3: pass_src (8-deep) FUSED with t-direction sort ----------------
__global__ __launch_bounds__(256) void pass_src_sortT_kernel(
    const int* __restrict__ rowstart_s,
    const int* __restrict__ tgt_sorted,
    const hf* __restrict__ P16,
    const hf* __restrict__ PP16,
    const float* __restrict__ enpsi,
    hf* __restrict__ AW16,
    const unsigned* __restrict__ ep_t, const int* __restrict__ gsc_t,
    int* __restrict__ src_sorted, int* __restrict__ rowstart_t,
    int nBkt, int nNodes, int nEdges)
{
    __shared__ int hist[32], pref[32], cur[32];
    const int tid = threadIdx.x;

    if (blockIdx.x >= PS_NB) {
        bucket_sort_body(ep_t, gsc_t, src_sorted, rowstart_t,
                         blockIdx.x - PS_NB, nBkt, nNodes, nEdges, hist, pref, cur, tid);
        return;
    }

    const int grp = tid >> 4;
    const int l = tid & 15;

    for (int n = blockIdx.x * 16 + grp; n < nNodes; n += PS_NB * 16) {
        const int beg = rowstart_s[n];
        const int end = rowstart_s[n + 1];
        const float2 pr = ((const float2*)(P16 + (size_t)n * D))[l];
        const hf* pq = (const hf*)&pr;
        const float p0 = pq[0], p1 = pq[1], p2 = pq[2], p3 = pq[3];
        float bden = 0.f, ssum = 0.f;

        int k = beg;
        for (; k + 7 < end; k += 8) {
            int tv[8]; float2 rv[8]; float ev[8];
            #pragma unroll
            for (int u = 0; u < 8; ++u) tv[u] = tgt_sorted[k + u];
            #pragma unroll
            for (int u = 0; u < 8; ++u) rv[u] = ((const float2*)(PP16 + (size_t)tv[u] * D))[l];
            #pragma unroll
            for (int u = 0; u < 8; ++u) ev[u] = enpsi[tv[u]];
            float sc[8];
            #pragma unroll
            for (int u = 0; u < 8; ++u) {
                const hf* q = (const hf*)&rv[u];
                sc[u] = (float)q[0] * p0 + (float)q[1] * p1 + (float)q[2] * p2 + (float)q[3] * p3;
            }
            #pragma unroll
            for (int off = 8; off >= 1; off >>= 1) {
                #pragma unroll
                for (int u = 0; u < 8; ++u) sc[u] += __shfl_xor(sc[u], off, 64);
            }
            #pragma unroll
            for (int u = 0; u < 8; ++u) {
                const float bn = __expf(sc[u]);
                bden += bn;
                ssum += bn * ev[u];
            }
        }
        for (; k + 3 < end; k += 4) {
            int tv[4]; float2 rv[4]; float ev[4];
            #pragma unroll
            for (int u = 0; u < 4; ++u) tv[u] = tgt_sorted[k + u];
            #pragma unroll
            for (int u = 0; u < 4; ++u) rv[u] = ((const float2*)(PP16 + (size_t)tv[u] * D))[l];
            #pragma unroll
            for (int u = 0; u < 4; ++u) ev[u] = enpsi[tv[u]];
            float sc[4];
            #pragma unroll
            for (int u = 0; u < 4; ++u) {
                const hf* q = (const hf*)&rv[u];
                sc[u] = (float)q[0] * p0 + (float)q[1] * p1 + (float)q[2] * p2 + (float)q[3] * p3;
            }
            #pragma unroll
            for (int off = 8; off >= 1; off >>= 1) {
                #pragma unroll
                for (int u = 0; u < 4; ++u) sc[u] += __shfl_xor(sc[u], off, 64);
            }
            #pragma unroll
            for (int u = 0; u < 4; ++u) {
                const float bn = __expf(sc[u]);
                bden += bn;
                ssum += bn * ev[u];
            }
        }
        for (; k < end; ++k) {
            const int t = tgt_sorted[k];
            const float2 r = ((const float2*)(PP16 + (size_t)t * D))[l];
            const float et = enpsi[t];
            const hf* q = (const hf*)&r;
            float a2 = (float)q[0] * p0 + (float)q[1] * p1 + (float)q[2] * p2 + (float)q[3] * p3;
            #pragma unroll
            for (int off = 8; off >= 1; off >>= 1) a2 += __shfl_xor(a2, off, 64);
            const float bn = __expf(a2);
            bden += bn;
            ssum += bn * et;
        }
        const float st = ssum / (bden + 1e-9f);
        const float d = -logf(st + 1e-8f);
        const float w = 1.0f - 1.0f / (1.0f + __expf(-(d - 0.5f)));
        float4* rowp = (float4*)(AW16 + ((size_t)n << 7));
        float4 rv = rowp[l];
        hf* q = (hf*)&rv;
        q[1] = (hf)((float)q[1] * w);
        q[3] = (hf)((float)q[3] * w);
        q[5] = (hf)((float)q[5] * w);
        q[7] = (hf)((float)q[7] * w);
        rowp[l] = rv;
    }
}

// ---------------- Pass tgt FUSED (8-deep): one float4 gather per edge ----------------
__global__ __launch_bounds__(256) void pass_tgt_fused_kernel(
    const int* __restrict__ rowstart_t,
    const int* __restrict__ src_sorted,
    const float* __restrict__ h,
    const hf* __restrict__ AW16,
    hf* __restrict__ m16,
    int nNodes)
{
    const int grp = threadIdx.x >> 4;
    const int l = threadIdx.x & 15;

    for (int n = blockIdx.x * 16 + grp; n < nNodes; n += gridDim.x * 16) {
        const int beg = rowstart_t[n];
        const int end = rowstart_t[n + 1];
        const float4 htv = ((const float4*)(h + (size_t)n * D))[l];
        float aden = 0.f;
        float m0 = 0.f, m1 = 0.f, m2 = 0.f, m3 = 0.f;

        int k = beg;
        for (; k + 7 < end; k += 8) {
            int sv[8]; float4 rv[8];
            #pragma unroll
            for (int u = 0; u < 8; ++u) sv[u] = src_sorted[k + u];
            #pragma unroll
            for (int u = 0; u < 8; ++u) rv[u] = ((const float4*)(AW16 + ((size_t)sv[u] << 7)))[l];
            float sc[8];
            #pragma unroll
            for (int u = 0; u < 8; ++u) {
                const hf* q = (const hf*)&rv[u];
                sc[u] = (float)q[0] * htv.x + (float)q[2] * htv.y
                      + (float)q[4] * htv.z + (float)q[6] * htv.w;
            }
            #pragma unroll
            for (int off = 8; off >= 1; off >>= 1) {
                #pragma unroll
                for (int u = 0; u < 8; ++u) sc[u] += __shfl_xor(sc[u], off, 64);
            }
            #pragma unroll
            for (int u = 0; u < 8; ++u) {
                const float an = __expf(sc[u]);
                aden += an;
                const hf* q = (const hf*)&rv[u];
                m0 += an * (float)q[1];
                m1 += an * (float)q[3];
                m2 += an * (float)q[5];
                m3 += an * (float)q[7];
            }
        }
        for (; k + 3 < end; k += 4) {
            int sv[4]; float4 rv[4];
            #pragma unroll
            for (int u = 0; u < 4; ++u) sv[u] = src_sorted[k + u];
            #pragma unroll
            for (int u = 0; u < 4; ++u) rv[u] = ((const float4*)(AW16 + ((size_t)sv[u] << 7)))[l];
            float sc[4];
            #pragma unroll
            for (int u = 0; u < 4; ++u) {
                const hf* q = (const hf*)&rv[u];
                sc[u] = (float)q[0] * htv.x + (float)q[2] * htv.y
                      + (float)q[4] * htv.z + (float)q[6] * htv.w;
            }
            #pragma unroll
            for (int off = 8; off >= 1; off >>= 1) {
                #pragma unroll
                for (int u = 0; u < 4; ++u) sc[u] += __shfl_xor(sc[u], off, 64);
            }
            #pragma unroll
            for (int u = 0; u < 4; ++u) {
                const float an = __expf(sc[u]);
                aden += an;
                const hf* q = (const hf*)&rv[u];
                m0 += an * (float)q[1];
                m1 += an * (float)q[3];
                m2 += an * (float)q[5];
                m3 += an * (float)q[7];
            }
        }
        for (; k < end; ++k) {
            const int s = src_sorted[k];
            const float4 r = ((const float4*)(AW16 + ((size_t)s << 7)))[l];
            const hf* q = (const hf*)&r;
            float a1 = (float)q[0] * htv.x + (float)q[2] * htv.y
                     + (float)q[4] * htv.z + (float)q[6] * htv.w;
            #pragma unroll
            for (int off = 8; off >= 1; off >>= 1) a1 += __shfl_xor(a1, off, 64);
            const float an = __expf(a1);
            aden += an;
            m0 += an * (float)q[1];
            m1 += an * (float)q[3];
            m2 += an * (float)q[5];
            m3 += an * (float)q[7];
        }

        const float idn = 1.0f / (aden + 1e-9f);
        hf o4[4];
        o4[0] = (hf)(m0 * idn);
        o4[1] = (hf)(m1 * idn);
        o4[2] = (hf)(m2 * idn);
        o4[3] = (hf)(m3 * idn);
        ((float2*)(m16 + (size_t)n * D))[l] = *(const float2*)o4;
    }
}

// ---------------- Final: streaming matmuls, 4 nodes per thread + LN ----------------
__global__ __launch_bounds__(512) void final_kernel(
    const float* __restrict__ h,
    const hf* __restrict__ m16,
    const float* __restrict__ W_self_w, const float* __restrict__ W_self_b,
    const float* __restrict__ W_A_w,    const float* __restrict__ W_A_b,
    const float* __restrict__ W_str_w,  const float* __restrict__ W_str_b,
    const float* __restrict__ ln_g,     const float* __restrict__ ln_b,
    float* __restrict__ out,
    int nNodes)
{
    __shared__ hf2 sWs2[32][D];
    __shared__ hf2 sWa2[32][D];
    __shared__ float sWstr[6 * D];
    __shared__ float sBias[D];
    __shared__ float sG[D], sB[D];
    __shared__ hf hall[32][D];
    __shared__ hf mall[32][D];

    const int tid = threadIdx.x;
    for (int idx = tid; idx < 32 * D; idx += 512) {
        const int k2 = idx >> 6, j = idx & 63;
        sWs2[k2][j] = hf2{(hf)W_self_w[(2 * k2) * D + j], (hf)W_self_w[(2 * k2 + 1) * D + j]};
        sWa2[k2][j] = hf2{(hf)W_A_w[(2 * k2) * D + j],    (hf)W_A_w[(2 * k2 + 1) * D + j]};
    }
    for (int i = tid; i < 6 * D; i += 512) sWstr[i] = W_str_w[i];
    if (tid < D) {
        sBias[tid] = W_self_b[tid] + W_A_b[tid] + W_str_b[tid];
        sG[tid] = ln_g[tid];
        sB[tid] = ln_b[tid];
    }

    const int n0 = blockIdx.x * 32;
    {
        const int base = tid * 4;
        const int ln = base >> 6;
        const int col = base & 63;
        const int n = n0 + ln;
        if (n < nNodes) {
            const float4 v = *(const float4*)(h + (size_t)n * D + col);
            hall[ln][col]     = (hf)v.x;
            hall[ln][col + 1] = (hf)v.y;
            hall[ln][col + 2] = (hf)v.z;
            hall[ln][col + 3] = (hf)v.w;
            *(uint2*)&mall[ln][col] = *(const uint2*)(m16 + (size_t)n * D + col);
        }
    }
    __syncthreads();

    const int g = tid >> 6, j = tid & 63;
    const int ln0 = 4 * g;

    float acc[4];
    #pragma unroll
    for (int m = 0; m < 4; ++m) acc[m] = sBias[j];

    const hf2* hr0 = (const hf2*)hall[ln0 + 0];
    const hf2* hr1 = (const hf2*)hall[ln0 + 1];
    const hf2* hr2 = (const hf2*)hall[ln0 + 2];
    const hf2* hr3 = (const hf2*)hall[ln0 + 3];
    const hf2* mr0 = (const hf2*)mall[ln0 + 0];
    const hf2* mr1 = (const hf2*)mall[ln0 + 1];
    const hf2* mr2 = (const hf2*)mall[ln0 + 2];
    const hf2* mr3 = (const hf2*)mall[ln0 + 3];

    #pragma unroll 8
    for (int k2 = 0; k2 < 32; ++k2) {
        const hf2 ws = sWs2[k2][j];
        const hf2 wa = sWa2[k2][j];
        acc[0] = fdot2f(ws, hr0[k2], acc[0]);
        acc[0] = fdot2f(wa, mr0[k2], acc[0]);
        acc[1] = fdot2f(ws, hr1[k2], acc[1]);
        acc[1] = fdot2f(wa, mr1[k2], acc[1]);
        acc[2] = fdot2f(ws, hr2[k2], acc[2]);
        acc[2] = fdot2f(wa, mr2[k2], acc[2]);
        acc[3] = fdot2f(ws, hr3[k2], acc[3]);
        acc[3] = fdot2f(wa, mr3[k2], acc[3]);
    }
    #pragma unroll
    for (int k = 0; k < 6; ++k) {
        const float w = sWstr[k * D + j];
        acc[0] += (float)hall[ln0 + 0][k] * w;
        acc[1] += (float)hall[ln0 + 1][k] * w;
        acc[2] += (float)hall[ln0 + 2][k] * w;
        acc[3] += (float)hall[ln0 + 3][k] * w;
    }

    float pre[4], mu[4], vv[4];
    #pragma unroll
    for (int m = 0; m < 4; ++m)
        pre[m] = fmaxf(acc[m], 0.f) + (float)hall[ln0 + m][j];

    #pragma unroll
    for (int m = 0; m < 4; ++m) mu[m] = pre[m];
    #pragma unroll
    for (int off = 32; off >= 1; off >>= 1) {
        #pragma unroll
        for (int m = 0; m < 4; ++m) mu[m] += __shfl_xor(mu[m], off, 64);
    }
    #pragma unroll
    for (int m = 0; m < 4; ++m) {
        mu[m] *= (1.0f / 64.0f);
        const float diff = pre[m] - mu[m];
        vv[m] = diff * diff;
    }
    #pragma unroll
    for (int off = 32; off >= 1; off >>= 1) {
        #pragma unroll
        for (int m = 0; m < 4; ++m) vv[m] += __shfl_xor(vv[m], off, 64);
    }
    #pragma unroll
    for (int m = 0; m < 4; ++m) {
        const int n = n0 + ln0 + m;
        if (n < nNodes) {
            const float diff = pre[m] - mu[m];
            out[(size_t)n * D + j] = diff * rsqrtf(vv[m] * (1.0f / 64.0f) + 1e-5f) * sG[j] + sB[j];
        }
    }
}

extern "C" void kernel_launch(void* const* d_in, const int* in_sizes, int n_in,
                              void* d_out, int out_size, void* d_ws, size_t ws_size,
                              hipStream_t stream) {
    const int* edge       = (const int*)d_in[0];
    const float* h        = (const float*)d_in[1];
    const float* W_att    = (const float*)d_in[2];
    const float* phi_w    = (const float*)d_in[3];
    const float* phi_b    = (const float*)d_in[4];
    const float* W_p      = (const float*)d_in[5];
    const float* W_pp     = (const float*)d_in[6];
    const float* fdef_w   = (const float*)d_in[7];
    const float* fdef_b   = (const float*)d_in[8];
    const float* W_self_w = (const float*)d_in[9];
    const float* W_self_b = (const float*)d_in[10];
    const float* W_A_w    = (const float*)d_in[11];
    const float* W_A_b    = (const float*)d_in[12];
    const float* W_str_w  = (const float*)d_in[13];
    const float* W_str_b  = (const float*)d_in[14];
    const float* ln_g     = (const float*)d_in[15];
    const float* ln_b     = (const float*)d_in[16];

    const int E = in_sizes[0] / 2;
    const int nNodes = in_sizes[1] / D;
    const int* srcI = edge;
    const int* tgtI = edge + E;
    const int nBkt = (nNodes + 31) / 32;
    const int L = nBkt * NB;
    const int nbNode = (nNodes + 31) / 32;

    char* ws = (char*)d_ws;
    size_t off = 0;
    auto alloc = [&](size_t bytes) { char* p = ws + off; off = (off + bytes + 255) & ~(size_t)255; return p; };

    hf*       AW16      = (hf*)      alloc((size_t)nNodes * 2 * D * 2);
    hf*       P16       = (hf*)      alloc((size_t)nNodes * D * 2);
    hf*       PP16      = (hf*)      alloc((size_t)nNodes * D * 2);
    hf*       m16       = (hf*)      alloc((size_t)nNodes * D * 2);
    float*    enpsi     = (float*)   alloc((size_t)nNodes * 4);
    int*      ghist_t   = (int*)     alloc((size_t)L * 4);
    int*      ghist_s   = (int*)     alloc((size_t)L * 4);
    int*      gsc_t     = (int*)     alloc((size_t)L * 4);
    int*      gsc_s     = (int*)     alloc((size_t)L * 4);
    unsigned* ep_t      = (unsigned*)alloc((size_t)E * 4);
    unsigned* ep_s      = (unsigned*)alloc((size_t)E * 4);
    int*      src_sorted= (int*)     alloc((size_t)E * 4);
    int*      tgt_sorted= (int*)     alloc((size_t)E * 4);
    int*      rowstart_t= (int*)     alloc(((size_t)nNodes + 1) * 4);
    int*      rowstart_s= (int*)     alloc(((size_t)nNodes + 1) * 4);
    int*      bsum      = (int*)     alloc((size_t)2 * SCAN_NB * 4);

    // K1: node_pre || bucket_hist (both directions)
    node_pre_hist_kernel<<<nbNode + 2 * NB, 512, 0, stream>>>(
        h, W_att, W_p, W_pp, phi_w, phi_b, fdef_w, fdef_b,
        tgtI, srcI, ghist_t, ghist_s,
        AW16, P16, PP16, enpsi, nNodes, nbNode, nBkt, E);

    scan_partial_kernel<<<2 * SCAN_NB, 256, 0, stream>>>(ghist_t, ghist_s, bsum, L);
    scan_bsum_kernel<<<1, 2 * SCAN_NB, 0, stream>>>(bsum);
    scan_final_kernel<<<2 * SCAN_NB, 256, 0, stream>>>(
        ghist_t, ghist_s, bsum, gsc_t, gsc_s, L);

    bucket_scatter_kernel<<<2 * NB, 256, 0, stream>>>(
        tgtI, srcI, gsc_t, gsc_s, ep_t, ep_s, nBkt, E);

    bucket_sort_s_kernel<<<nBkt, 256, 0, stream>>>(
        ep_s, gsc_s, tgt_sorted, rowstart_s, nBkt, nNodes, E);

    // K3: pass_src || t-direction sort
    pass_src_sortT_kernel<<<PS_NB + nBkt, 256, 0, stream>>>(
        rowstart_s, tgt_sorted, P16, PP16, enpsi, AW16,
        ep_t, gsc_t, src_sorted, rowstart_t, nBkt, nNodes, E);

    pass_tgt_fused_kernel<<<2048, 256, 0, stream>>>(
        rowstart_t, src_sorted, h, AW16, m16, nNodes);

    final_kernel<<<nbNode, 512, 0, stream>>>(
        h, m16, W_self_w, W_self_b, W_A_w, W_A_b,
        W_str_w, W_str_b, ln_g, ln_b, (float*)d_out, nNodes);
}